// Round 4
// baseline (45.567 us; speedup 1.0000x reference)
//
#include <hip/hip_runtime.h>

#define NB 2
#define NCK 8                    // tracked components 1..8 (comp 0 dropped in epilogue)
#define NVAL (NCK * 2)           // {inter,count} x 8 per batch
#define NSL 32                   // per-block partial row: b0[16] | b1[16]
#define SMOOTHF 1e-5f

// process one voxel: A0,A1 logits, T true label (0/1), C component id (0 = ignored)
#define PROC(A0, A1, T, C) do { \
    float d_ = (A0) - (A1); \
    float p_ = 1.0f / (1.0f + __expf((T) ? d_ : -d_)); \
    _Pragma("unroll") \
    for (int j_ = 0; j_ < NCK; ++j_) { \
        float m_ = ((C) == j_ + 1) ? 1.0f : 0.0f; \
        acc[2 * j_] = fmaf(m_, p_, acc[2 * j_]); \
        acc[2 * j_ + 1] += m_; \
    } } while (0)

__global__ __launch_bounds__(256) void cc_accum(
        const float* __restrict__ y_pred,
        const int* __restrict__ y,
        const int* __restrict__ comp,
        float* __restrict__ partial,   // [nblk][NSL] row-major
        int V4, int BPB, int QB) {
    const int b   = (blockIdx.x >= BPB) ? 1 : 0;   // batch is block-uniform
    const int blk = blockIdx.x - b * BPB;

    const float* p0 = y_pred + (size_t)b * 2 * ((size_t)V4 * 4);
    const float* p1 = p0 + (size_t)V4 * 4;
    const int4* yq = (const int4*)y    + (size_t)b * V4;
    const int4* cq = (const int4*)comp + (size_t)b * V4;

    float acc[NVAL];
    #pragma unroll
    for (int i = 0; i < NVAL; ++i) acc[i] = 0.0f;

    // contiguous chunk [blk*QB, blk*QB+QB) of quads; threads stride 256 inside
    int vend = blk * QB + QB;
    if (vend > V4) vend = V4;
    const int v0 = blk * QB + threadIdx.x;

    for (int base = 0; base < QB; base += 1024) {
        #pragma unroll
        for (int k = 0; k < 4; k += 2) {
            int va = v0 + base + k * 256;
            int vb = va + 256;
            const bool ma = va < vend, mb = vb < vend;
            const int vca = ma ? va : (vend - 1);   // clamp: stay in-bounds
            const int vcb = mb ? vb : (vend - 1);

            // 8 x dwordx4 issued before any compute
            const float4 a0a = ((const float4*)p0)[vca];
            const float4 a1a = ((const float4*)p1)[vca];
            int4 ta = yq[vca];
            int4 ca = cq[vca];
            const float4 a0b = ((const float4*)p0)[vcb];
            const float4 a1b = ((const float4*)p1)[vcb];
            int4 tb = yq[vcb];
            int4 cb = cq[vcb];

            // invalid lanes -> component 0 (the dropped bin): zero epilogue cost
            if (!ma) { ca.x = 0; ca.y = 0; ca.z = 0; ca.w = 0; }
            if (!mb) { cb.x = 0; cb.y = 0; cb.z = 0; cb.w = 0; }

            PROC(a0a.x, a1a.x, ta.x, ca.x);
            PROC(a0a.y, a1a.y, ta.y, ca.y);
            PROC(a0a.z, a1a.z, ta.z, ca.z);
            PROC(a0a.w, a1a.w, ta.w, ca.w);
            PROC(a0b.x, a1b.x, tb.x, cb.x);
            PROC(a0b.y, a1b.y, tb.y, cb.y);
            PROC(a0b.z, a1b.z, tb.z, cb.z);
            PROC(a0b.w, a1b.w, tb.w, cb.w);
        }
    }

    // wave butterfly reduce each of the 16 values
    #pragma unroll
    for (int i = 0; i < NVAL; ++i) {
        float s = acc[i];
        #pragma unroll
        for (int off = 32; off; off >>= 1) s += __shfl_xor(s, off);
        acc[i] = s;
    }

    // cross-wave combine, then one 128B store per block (32 floats)
    __shared__ float red[4][NVAL];
    const int lane = threadIdx.x & 63, wid = threadIdx.x >> 6;
    if (lane == 0) {
        #pragma unroll
        for (int i = 0; i < NVAL; ++i) red[wid][i] = acc[i];
    }
    __syncthreads();
    if (threadIdx.x < NSL) {
        const int j = threadIdx.x;          // 0..31 = b0 vals | b1 vals
        const int jb = j >> 4, jv = j & 15;
        float s = 0.0f;
        if (jb == b) s = red[0][jv] + red[1][jv] + red[2][jv] + red[3][jv];
        partial[(size_t)blockIdx.x * NSL + j] = s;
    }
}

__global__ __launch_bounds__(256) void cc_finish(
        const float* __restrict__ partial, float* __restrict__ out, int nblk) {
    // column-sum of [nblk][32] via float4: thread's float4s all map to cols 4*(tid%8)+k
    float4 a = make_float4(0.f, 0.f, 0.f, 0.f);
    const float4* p4 = (const float4*)partial;
    const int nf = nblk * (NSL / 4);
    for (int f = threadIdx.x; f < nf; f += 256) {
        const float4 v = p4[f];
        a.x += v.x; a.y += v.y; a.z += v.z; a.w += v.w;
    }
    __shared__ float red[256][4];
    red[threadIdx.x][0] = a.x;
    red[threadIdx.x][1] = a.y;
    red[threadIdx.x][2] = a.z;
    red[threadIdx.x][3] = a.w;
    __syncthreads();
    __shared__ float fin[NSL];
    if (threadIdx.x < NSL) {
        const int c = threadIdx.x;
        const int grp = c >> 2, k = c & 3;   // contributors: tid = g*8 + grp
        float s = 0.0f;
        #pragma unroll 8
        for (int g = 0; g < 32; ++g) s += red[g * 8 + grp][k];
        fin[c] = s;
    }
    __syncthreads();
    if (threadIdx.x == 0) {
        // psum = tsum = count (softmax over 2 ch sums to 1; one-hot sums to 1)
        float total = 0.0f;
        for (int b = 0; b < NB; ++b) {
            float dsum = 0.0f, pc = 0.0f;
            for (int j = 0; j < NCK; ++j) {
                const float inter = fin[b * NVAL + 2 * j];
                const float cnt   = fin[b * NVAL + 2 * j + 1];
                if (cnt > 0.0f) {
                    dsum += 1.0f - (2.0f * inter + SMOOTHF) / (2.0f * cnt + SMOOTHF);
                    pc += 1.0f;
                }
            }
            total += dsum / fmaxf(pc, 1.0f);
        }
        out[0] = total / (float)NB;
    }
}

extern "C" void kernel_launch(void* const* d_in, const int* in_sizes, int n_in,
                              void* d_out, int out_size, void* d_ws, size_t ws_size,
                              hipStream_t stream) {
    const float* y_pred = (const float*)d_in[0];
    const int*   y      = (const int*)d_in[1];
    const int*   comp   = (const int*)d_in[2];
    float* out = (float*)d_out;
    float* ws  = (float*)d_ws;

    const int nvox = in_sizes[1];    // B * V = 8,192,000
    const int V    = nvox / NB;      // 4,096,000
    const int V4   = V / 4;          // 1,024,000 quads per batch

    int BPB = 1024;                  // blocks per batch -> 2048 total = 8/CU
    int cap_rows = (int)(ws_size / (NSL * sizeof(float)));
    if (2 * BPB > cap_rows) BPB = cap_rows / 2;
    if (BPB > V4) BPB = V4;
    if (BPB < 1) BPB = 1;
    const int QB = (V4 + BPB - 1) / BPB;   // 1000 quads per block for defaults
    const int nblk = 2 * BPB;

    cc_accum<<<dim3(nblk), dim3(256), 0, stream>>>(y_pred, y, comp, ws, V4, BPB, QB);
    cc_finish<<<dim3(1), dim3(256), 0, stream>>>(ws, out, nblk);
}

// Round 5
// 37.869 us; speedup vs baseline: 1.2033x; 1.2033x over previous
//
#include <hip/hip_runtime.h>

#define NB 2
#define NCK 8                    // tracked components 1..8 (comp 0 dropped in epilogue)
#define NVAL (NCK * 2)           // {inter,count} x 8 per batch
#define NSL 32                   // per-block partial row: b0[16] | b1[16]
#define SMOOTHF 1e-5f

// one voxel: A0,A1 logits, T true label (0/1), C component id (0 = ignored)
#define PROC(A0, A1, T, C) do { \
    float d_ = (A0) - (A1); \
    float p_ = 1.0f / (1.0f + __expf((T) ? d_ : -d_)); \
    _Pragma("unroll") \
    for (int j_ = 0; j_ < NCK; ++j_) { \
        float m_ = ((C) == j_ + 1) ? 1.0f : 0.0f; \
        acc[2 * j_] = fmaf(m_, p_, acc[2 * j_]); \
        acc[2 * j_ + 1] += m_; \
    } } while (0)

// epilogue shared by both accum variants: 16-val butterfly + cross-wave + 128B store
#define ACC_EPILOGUE() do { \
    _Pragma("unroll") \
    for (int i = 0; i < NVAL; ++i) { \
        float s = acc[i]; \
        _Pragma("unroll") \
        for (int off = 32; off; off >>= 1) s += __shfl_xor(s, off); \
        acc[i] = s; \
    } \
    __shared__ float red[4][NVAL]; \
    const int lane = threadIdx.x & 63, wid = threadIdx.x >> 6; \
    if (lane == 0) { \
        _Pragma("unroll") \
        for (int i = 0; i < NVAL; ++i) red[wid][i] = acc[i]; \
    } \
    __syncthreads(); \
    if (threadIdx.x < NSL) { \
        const int j = threadIdx.x, jb = j >> 4, jv = j & 15; \
        float s = 0.0f; \
        if (jb == b) s = red[0][jv] + red[1][jv] + red[2][jv] + red[3][jv]; \
        partial[(size_t)blockIdx.x * NSL + j] = s; \
    } } while (0)

// Interleaved grid-stride (round-3 pattern), all NIT iterations' loads hoisted.
template <int NIT>
__global__ __launch_bounds__(256) void cc_accum_u(
        const float* __restrict__ y_pred,
        const int* __restrict__ y,
        const int* __restrict__ comp,
        float* __restrict__ partial,   // [nblk][NSL] row-major
        int V4, int BPB) {
    const int b   = (blockIdx.x >= BPB) ? 1 : 0;   // batch is block-uniform
    const int blk = blockIdx.x - b * BPB;
    const int stride = BPB * 256;

    const float* p0 = y_pred + (size_t)b * 2 * ((size_t)V4 * 4);
    const float* p1 = p0 + (size_t)V4 * 4;
    const int4* yq = (const int4*)y    + (size_t)b * V4;
    const int4* cq = (const int4*)comp + (size_t)b * V4;
    const int v0 = blk * 256 + threadIdx.x;

    // hoist ALL loads: NIT*4 dwordx4 in flight before any compute
    float4 A0[NIT], A1[NIT];
    int4 T[NIT], C[NIT];
    #pragma unroll
    for (int i = 0; i < NIT; ++i) {
        const int v = v0 + i * stride;
        const bool m = v < V4;
        const int vc = m ? v : 0;
        A0[i] = ((const float4*)p0)[vc];
        A1[i] = ((const float4*)p1)[vc];
        T[i]  = yq[vc];
        int4 cv = cq[vc];
        if (!m) { cv.x = 0; cv.y = 0; cv.z = 0; cv.w = 0; }  // dropped bin
        C[i] = cv;
    }

    float acc[NVAL];
    #pragma unroll
    for (int i = 0; i < NVAL; ++i) acc[i] = 0.0f;

    #pragma unroll
    for (int i = 0; i < NIT; ++i) {
        PROC(A0[i].x, A1[i].x, T[i].x, C[i].x);
        PROC(A0[i].y, A1[i].y, T[i].y, C[i].y);
        PROC(A0[i].z, A1[i].z, T[i].z, C[i].z);
        PROC(A0[i].w, A1[i].w, T[i].w, C[i].w);
    }

    ACC_EPILOGUE();
}

// Generic fallback (runtime trip count) — round-3 structure.
__global__ __launch_bounds__(256) void cc_accum_g(
        const float* __restrict__ y_pred,
        const int* __restrict__ y,
        const int* __restrict__ comp,
        float* __restrict__ partial,
        int V4, int BPB) {
    const int b   = (blockIdx.x >= BPB) ? 1 : 0;
    const int blk = blockIdx.x - b * BPB;
    const int stride = BPB * 256;

    const float* p0 = y_pred + (size_t)b * 2 * ((size_t)V4 * 4);
    const float* p1 = p0 + (size_t)V4 * 4;
    const int4* yq = (const int4*)y    + (size_t)b * V4;
    const int4* cq = (const int4*)comp + (size_t)b * V4;

    float acc[NVAL];
    #pragma unroll
    for (int i = 0; i < NVAL; ++i) acc[i] = 0.0f;

    for (int v = blk * 256 + threadIdx.x; v < V4; v += stride) {
        const float4 a0 = ((const float4*)p0)[v];
        const float4 a1 = ((const float4*)p1)[v];
        const int4 t = yq[v];
        const int4 c = cq[v];
        PROC(a0.x, a1.x, t.x, c.x);
        PROC(a0.y, a1.y, t.y, c.y);
        PROC(a0.z, a1.z, t.z, c.z);
        PROC(a0.w, a1.w, t.w, c.w);
    }

    ACC_EPILOGUE();
}

// Fused reduce+final: one block, 1024 threads, column-sum of [nblk][32].
__global__ __launch_bounds__(1024) void cc_finish(
        const float* __restrict__ partial, float* __restrict__ out, int nblk) {
    const int tid = threadIdx.x;
    const float4* p4 = (const float4*)partial;   // [nblk*8] float4s; col group = f%8
    const int nf = nblk * (NSL / 4);

    float4 a = make_float4(0.f, 0.f, 0.f, 0.f);
    for (int f = tid; f < nf; f += 1024) {       // independent loads, deep MLP
        const float4 v = p4[f];
        a.x += v.x; a.y += v.y; a.z += v.z; a.w += v.w;
    }

    __shared__ float4 red[1024];
    red[tid] = a;
    __syncthreads();
    if (tid < 256) {
        float4 r = red[tid];
        const float4 s1 = red[tid + 256], s2 = red[tid + 512], s3 = red[tid + 768];
        r.x += s1.x + s2.x + s3.x;
        r.y += s1.y + s2.y + s3.y;
        r.z += s1.z + s2.z + s3.z;
        r.w += s1.w + s2.w + s3.w;
        red[tid] = r;
    }
    __syncthreads();
    if (tid < 64) {
        float4 r = red[tid];
        const float4 s1 = red[tid + 64], s2 = red[tid + 128], s3 = red[tid + 192];
        r.x += s1.x + s2.x + s3.x;
        r.y += s1.y + s2.y + s3.y;
        r.z += s1.z + s2.z + s3.z;
        r.w += s1.w + s2.w + s3.w;
        red[tid] = r;
    }
    __syncthreads();
    __shared__ float fin[NSL];
    if (tid < NSL) {
        const int grp = tid >> 2, k = tid & 3;   // col = 4*(row%8)+k
        float s = 0.0f;
        #pragma unroll
        for (int g = 0; g < 8; ++g) {
            const float4 r = red[g * 8 + grp];
            s += (k == 0) ? r.x : (k == 1) ? r.y : (k == 2) ? r.z : r.w;
        }
        fin[tid] = s;
    }
    __syncthreads();
    if (tid == 0) {
        // psum = tsum = count (softmax over 2 ch sums to 1; one-hot sums to 1)
        float total = 0.0f;
        for (int b = 0; b < NB; ++b) {
            float dsum = 0.0f, pc = 0.0f;
            for (int j = 0; j < NCK; ++j) {
                const float inter = fin[b * NVAL + 2 * j];
                const float cnt   = fin[b * NVAL + 2 * j + 1];
                if (cnt > 0.0f) {
                    dsum += 1.0f - (2.0f * inter + SMOOTHF) / (2.0f * cnt + SMOOTHF);
                    pc += 1.0f;
                }
            }
            total += dsum / fmaxf(pc, 1.0f);
        }
        out[0] = total / (float)NB;
    }
}

extern "C" void kernel_launch(void* const* d_in, const int* in_sizes, int n_in,
                              void* d_out, int out_size, void* d_ws, size_t ws_size,
                              hipStream_t stream) {
    const float* y_pred = (const float*)d_in[0];
    const int*   y      = (const int*)d_in[1];
    const int*   comp   = (const int*)d_in[2];
    float* out = (float*)d_out;
    float* ws  = (float*)d_ws;

    const int nvox = in_sizes[1];    // B * V = 8,192,000
    const int V    = nvox / NB;      // 4,096,000
    const int V4   = V / 4;          // 1,024,000 quads per batch

    int BPB = 1024;                  // blocks per batch -> 2048 total = 8/CU
    int cap_rows = (int)(ws_size / (NSL * sizeof(float)));
    if (2 * BPB > cap_rows) BPB = cap_rows / 2;
    if (BPB > V4) BPB = V4;
    if (BPB < 1) BPB = 1;
    const int nblk = 2 * BPB;
    const int stride = BPB * 256;
    const int nit = (V4 + stride - 1) / stride;

    if (nit == 4)
        cc_accum_u<4><<<dim3(nblk), dim3(256), 0, stream>>>(y_pred, y, comp, ws, V4, BPB);
    else if (nit == 2)
        cc_accum_u<2><<<dim3(nblk), dim3(256), 0, stream>>>(y_pred, y, comp, ws, V4, BPB);
    else if (nit == 1)
        cc_accum_u<1><<<dim3(nblk), dim3(256), 0, stream>>>(y_pred, y, comp, ws, V4, BPB);
    else
        cc_accum_g<<<dim3(nblk), dim3(256), 0, stream>>>(y_pred, y, comp, ws, V4, BPB);

    cc_finish<<<dim3(1), dim3(1024), 0, stream>>>(ws, out, nblk);
}

// Round 6
// 31.176 us; speedup vs baseline: 1.4616x; 1.2147x over previous
//
#include <hip/hip_runtime.h>

#define NB 2
#define NCK 8                    // tracked components 1..8 (comp 0 dropped)
#define NVAL (NCK * 2)           // {inter,count} x 8 per batch
#define NBINS (NB * NVAL)        // 32 global bins
#define SMOOTHF 1e-5f

// Per-thread private LDS bins: 9 float2 {inter,count}, stride 18 floats = 72 B
// (8B-aligned -> ds_read_b64/ds_write_b64). Non-atomic RMW: each lane owns its row.
#define TROW 18

__global__ __launch_bounds__(256) void cc_accum(
        const float* __restrict__ y_pred,
        const int* __restrict__ y,
        const int* __restrict__ comp,
        float* __restrict__ partial,   // [NBINS][nblk], column = global blockIdx
        int V4, int BPB, int nblk) {
    __shared__ __align__(8) float sacc[256 * TROW + 16 * 16];
    float* redbuf = &sacc[256 * TROW];

    float2* mybins = (float2*)&sacc[threadIdx.x * TROW];
    #pragma unroll
    for (int i = 0; i < 9; ++i) mybins[i] = make_float2(0.0f, 0.0f);
    // no barrier needed: each thread touches only its own row until drain

    const int b   = (blockIdx.x >= BPB) ? 1 : 0;   // batch is block-uniform
    const int blk = blockIdx.x - b * BPB;
    const int stride = BPB * 256;

    const float* p0 = y_pred + (size_t)b * 2 * ((size_t)V4 * 4);
    const float* p1 = p0 + (size_t)V4 * 4;
    const int4* yq = (const int4*)y    + (size_t)b * V4;
    const int4* cq = (const int4*)comp + (size_t)b * V4;

    for (int v = blk * 256 + threadIdx.x; v < V4; v += stride) {
        const float4 a0 = ((const float4*)p0)[v];
        const float4 a1 = ((const float4*)p1)[v];
        const int4 t = yq[v];
        const int4 c = cq[v];

        // p_true = softmax(y_pred)[true] = 1/(1+exp(t ? a0-a1 : a1-a0))
        {
            const float d = a0.x - a1.x;
            const float p = 1.0f / (1.0f + __expf(t.x ? d : -d));
            float2 s = mybins[c.x]; s.x += p; s.y += 1.0f; mybins[c.x] = s;
        }
        {
            const float d = a0.y - a1.y;
            const float p = 1.0f / (1.0f + __expf(t.y ? d : -d));
            float2 s = mybins[c.y]; s.x += p; s.y += 1.0f; mybins[c.y] = s;
        }
        {
            const float d = a0.z - a1.z;
            const float p = 1.0f / (1.0f + __expf(t.z ? d : -d));
            float2 s = mybins[c.z]; s.x += p; s.y += 1.0f; mybins[c.z] = s;
        }
        {
            const float d = a0.w - a1.w;
            const float p = 1.0f / (1.0f + __expf(t.w ? d : -d));
            float2 s = mybins[c.w]; s.x += p; s.y += 1.0f; mybins[c.w] = s;
        }
    }
    __syncthreads();

    // Drain: value v = tid&15 (v = 2*(comp-1)+part), group g = tid>>4 sums 16 rows.
    {
        const int v = threadIdx.x & 15, g = threadIdx.x >> 4;
        const int off = ((v >> 1) + 1) * 2 + (v & 1);   // skip bin 0
        float s = 0.0f;
        #pragma unroll
        for (int k = 0; k < 16; ++k)
            s += sacc[(g * 16 + k) * TROW + off];
        redbuf[v * 16 + g] = s;
    }
    __syncthreads();
    if (threadIdx.x < NVAL) {
        float s = 0.0f;
        #pragma unroll
        for (int g = 0; g < 16; ++g) s += redbuf[threadIdx.x * 16 + g];
        partial[(size_t)(b * NVAL + threadIdx.x) * nblk + blockIdx.x] = s;
    }
}

__global__ __launch_bounds__(256) void cc_reduce(
        const float* __restrict__ partial, float* __restrict__ fin,
        int half, int nblk) {
    const int bin = blockIdx.x;            // 0..NBINS-1
    const int b = (bin >= NVAL) ? 1 : 0;   // which batch's columns hold data
    const int c0 = b * half;
    float s = 0.0f;
    for (int i = threadIdx.x; i < half; i += 256)
        s += partial[(size_t)bin * nblk + c0 + i];
    #pragma unroll
    for (int off = 32; off; off >>= 1) s += __shfl_xor(s, off);
    __shared__ float w4[4];
    if ((threadIdx.x & 63) == 0) w4[threadIdx.x >> 6] = s;
    __syncthreads();
    if (threadIdx.x == 0) fin[bin] = w4[0] + w4[1] + w4[2] + w4[3];
}

__global__ void cc_final(const float* __restrict__ fin, float* __restrict__ out) {
    // psum = tsum = count (softmax over 2 ch sums to 1; one-hot sums to 1).
    float total = 0.0f;
    for (int b = 0; b < NB; ++b) {
        float dsum = 0.0f, pc = 0.0f;
        for (int j = 0; j < NCK; ++j) {
            const float inter = fin[b * NVAL + 2 * j];
            const float cnt   = fin[b * NVAL + 2 * j + 1];
            if (cnt > 0.0f) {
                dsum += 1.0f - (2.0f * inter + SMOOTHF) / (2.0f * cnt + SMOOTHF);
                pc += 1.0f;
            }
        }
        total += dsum / fmaxf(pc, 1.0f);
    }
    out[0] = total / (float)NB;
}

extern "C" void kernel_launch(void* const* d_in, const int* in_sizes, int n_in,
                              void* d_out, int out_size, void* d_ws, size_t ws_size,
                              hipStream_t stream) {
    const float* y_pred = (const float*)d_in[0];
    const int*   y      = (const int*)d_in[1];
    const int*   comp   = (const int*)d_in[2];
    float* out = (float*)d_out;
    float* ws  = (float*)d_ws;

    const int nvox = in_sizes[1];    // B * V = 8,192,000
    const int V    = nvox / NB;      // 4,096,000
    const int V4   = V / 4;          // 1,024,000 quads per batch

    int BPB = 1024;                  // blocks per batch -> 2048 total = 8/CU
    int cap_rows = (int)((ws_size / sizeof(float) - NBINS) / NBINS);
    if (2 * BPB > cap_rows) BPB = cap_rows / 2;
    if (BPB > V4) BPB = V4;
    if (BPB < 1) BPB = 1;
    const int nblk = 2 * BPB;

    float* fin = ws + (size_t)NBINS * nblk;

    cc_accum<<<dim3(nblk), dim3(256), 0, stream>>>(y_pred, y, comp, ws, V4, BPB, nblk);
    cc_reduce<<<dim3(NBINS), dim3(256), 0, stream>>>(ws, fin, BPB, nblk);
    cc_final<<<dim3(1), dim3(1), 0, stream>>>(fin, out);
}